// Round 2
// baseline (745.991 us; speedup 1.0000x reference)
//
#include <hip/hip_runtime.h>
#include <math.h>

#define EMBED 1024
#define HIDDEN 4096
#define ROWS_CAP 3072
#define LDA 36  // LDS row stride in shorts: l15*18 mod 32 covers 16 banks -> ~conflict-free

typedef short short8 __attribute__((ext_vector_type(8)));
typedef float f32x4 __attribute__((ext_vector_type(4)));

__device__ __forceinline__ short f2bf(float f) {
  __bf16 h = (__bf16)f;
  return __builtin_bit_cast(short, h);
}

__device__ __forceinline__ short8 pack8(float4 a, float4 b) {
  short8 r;
  r[0] = f2bf(a.x); r[1] = f2bf(a.y); r[2] = f2bf(a.z); r[3] = f2bf(a.w);
  r[4] = f2bf(b.x); r[5] = f2bf(b.y); r[6] = f2bf(b.z); r[7] = f2bf(b.w);
  return r;
}

// ---------------- router: logits -> softmax -> top2 -> counts ----------------
__global__ __launch_bounds__(256) void router_kernel(
    const float* __restrict__ x, const float* __restrict__ gw,
    int* __restrict__ count, int2* __restrict__ t_idx, float2* __restrict__ t_w) {
  int t = blockIdx.x * 4 + (threadIdx.x >> 6);
  int lane = threadIdx.x & 63;
  const float* xr = x + (size_t)t * EMBED;
  float acc[8] = {0.f,0.f,0.f,0.f,0.f,0.f,0.f,0.f};
#pragma unroll
  for (int c = 0; c < 4; ++c) {
    float4 xv = *(const float4*)(xr + lane * 4 + c * 256);
#pragma unroll
    for (int e = 0; e < 8; ++e) {
      float4 gv = *(const float4*)(gw + e * EMBED + lane * 4 + c * 256);
      acc[e] += xv.x * gv.x + xv.y * gv.y + xv.z * gv.z + xv.w * gv.w;
    }
  }
#pragma unroll
  for (int e = 0; e < 8; ++e) {
#pragma unroll
    for (int off = 32; off > 0; off >>= 1) acc[e] += __shfl_down(acc[e], off);
  }
  if (lane == 0) {
    float m = acc[0];
#pragma unroll
    for (int e = 1; e < 8; ++e) m = fmaxf(m, acc[e]);
    float p[8]; float s = 0.f;
#pragma unroll
    for (int e = 0; e < 8; ++e) { p[e] = expf(acc[e] - m); s += p[e]; }
    float inv = 1.0f / s;
#pragma unroll
    for (int e = 0; e < 8; ++e) p[e] *= inv;
    int i0 = 0; float p0 = p[0];
#pragma unroll
    for (int e = 1; e < 8; ++e) if (p[e] > p0) { p0 = p[e]; i0 = e; }
    int i1 = -1; float p1 = -1.f;
#pragma unroll
    for (int e = 0; e < 8; ++e) if (e != i0 && p[e] > p1) { p1 = p[e]; i1 = e; }
    float denom = p0 + p1 + 1e-9f;
    float w0 = p0 / denom, w1 = p1 / denom;
    atomicAdd(&count[i0], 1);
    atomicAdd(&count[i1], 1);
    t_idx[t] = make_int2(i0, i1);
    t_w[t] = make_float2(w0, w1);
  }
}

// ---------------- assign: 128-aligned bases + compact row map ----------------
__global__ __launch_bounds__(256) void assign_kernel(
    const int* __restrict__ count, int* __restrict__ base,
    const int2* __restrict__ t_idx, const float2* __restrict__ t_w,
    int* __restrict__ row_token, float* __restrict__ row_w, int T) {
  __shared__ int s_base[8];
  __shared__ int s_cur[8];
  int tid = threadIdx.x;
  for (int i = tid; i < ROWS_CAP; i += 256) row_token[i] = -1;
  if (tid == 0) {
    int b = 0;
    for (int e = 0; e < 8; ++e) {
      s_base[e] = b; base[e] = b;
      b += (count[e] + 127) & ~127;
    }
  }
  if (tid < 8) s_cur[tid] = 0;
  __syncthreads();
  for (int t = tid; t < T; t += 256) {
    int2 ii = t_idx[t]; float2 ww = t_w[t];
    int p = atomicAdd(&s_cur[ii.x], 1);
    int r = s_base[ii.x] + p;
    row_token[r] = t; row_w[r] = ww.x;
    p = atomicAdd(&s_cur[ii.y], 1);
    r = s_base[ii.y] + p;
    row_token[r] = t; row_w[r] = ww.y;
  }
}

// ---------------- FFN layer 1: H = gelu(X_e @ W1[e] + b1[e]) ----------------
// grid (32, 128): x = n-tile (128 over HIDDEN), y = e*16 + mt (64-row tiles)
// Double-buffered LDS, 1 barrier/iter, register prefetch of next k-chunk.
__global__ __launch_bounds__(256, 4) void ffn1_kernel(
    const float* __restrict__ x, const float* __restrict__ w1,
    const float* __restrict__ b1, const int* __restrict__ count,
    const int* __restrict__ base, const int* __restrict__ row_token,
    unsigned short* __restrict__ H) {
  int nt = blockIdx.x;
  int e  = blockIdx.y >> 4;
  int mt = blockIdx.y & 15;
  int cnt = count[e];
  if (mt * 64 >= cnt) return;
  int base_e = base[e];
  int n0 = nt * 128;
  const float* w1e = w1 + (size_t)e * EMBED * HIDDEN;

  __shared__ __align__(16) short As[2][64 * LDA];
  __shared__ __align__(16) short Bs[2][128 * LDA];

  int tid = threadIdx.x;
  // A staging: 4 threads/row, 8 k-elems each
  int arow = tid >> 2;
  int akq  = (tid & 3) * 8;
  int a_pos = mt * 64 + arow;
  int a_tok = (a_pos < cnt) ? row_token[base_e + a_pos] : -1;
  const float* a_src = x + (size_t)(a_tok < 0 ? 0 : a_tok) * EMBED + akq;
  short* As_dst0 = &As[0][arow * LDA + akq];
  short* As_dst1 = &As[1][arow * LDA + akq];
  // B staging: coalesced along n, strided over k; LDS layout [n][k] k-contig
  int bn  = tid & 127;
  int bk0 = (tid >> 7) * 16;
  const float* b_src = w1e + (size_t)(n0 + bn);
  short* Bs_dst0 = &Bs[0][bn * LDA + bk0];
  short* Bs_dst1 = &Bs[1][bn * LDA + bk0];

  int lane = tid & 63, wv = tid >> 6;
  int wm = wv & 1, wn = wv >> 1;
  int quad = lane >> 4, l15 = lane & 15;

  f32x4 acc[2][4];
#pragma unroll
  for (int i = 0; i < 2; ++i)
#pragma unroll
    for (int j = 0; j < 4; ++j) acc[i][j] = (f32x4){0.f, 0.f, 0.f, 0.f};

  // prefetch k=0
  float4 va0 = *(const float4*)(a_src);
  float4 va1 = *(const float4*)(a_src + 4);
  float bv[16];
#pragma unroll
  for (int j = 0; j < 16; ++j) bv[j] = b_src[(size_t)(bk0 + j) * HIDDEN];

  int cur = 0;
  for (int kk = 0; kk < EMBED; kk += 32) {
    // pack and store current chunk to LDS[cur]
    short8 av = pack8(va0, va1);
    short8 blo, bhi;
#pragma unroll
    for (int j = 0; j < 8; ++j) { blo[j] = f2bf(bv[j]); bhi[j] = f2bf(bv[j + 8]); }
    short* ad = cur ? As_dst1 : As_dst0;
    short* bd = cur ? Bs_dst1 : Bs_dst0;
    *(short8*)ad = av;
    *(short8*)bd = blo;
    *(short8*)(bd + 8) = bhi;
    __syncthreads();

    // prefetch next chunk into registers (overlaps MFMA below)
    int kn = kk + 32; if (kn >= EMBED) kn = 0;
    va0 = *(const float4*)(a_src + kn);
    va1 = *(const float4*)(a_src + kn + 4);
#pragma unroll
    for (int j = 0; j < 16; ++j) bv[j] = b_src[(size_t)(kn + bk0 + j) * HIDDEN];

    // compute from LDS[cur]
    const short* Ab = &As[cur][(wm * 32 + l15) * LDA + quad * 8];
    const short* Bb = &Bs[cur][(wn * 64 + l15) * LDA + quad * 8];
    short8 af[2], bf4[4];
#pragma unroll
    for (int i = 0; i < 2; ++i) af[i] = *(const short8*)(Ab + i * 16 * LDA);
#pragma unroll
    for (int j = 0; j < 4; ++j) bf4[j] = *(const short8*)(Bb + j * 16 * LDA);
#pragma unroll
    for (int i = 0; i < 2; ++i)
#pragma unroll
      for (int j = 0; j < 4; ++j)
        acc[i][j] = __builtin_amdgcn_mfma_f32_16x16x32_bf16(af[i], bf4[j], acc[i][j], 0, 0, 0);
    cur ^= 1;
  }

  const float* b1e = b1 + e * HIDDEN;
#pragma unroll
  for (int i = 0; i < 2; ++i) {
    int rl = wm * 32 + i * 16 + quad * 4;
#pragma unroll
    for (int rg = 0; rg < 4; ++rg) {
      int pos = mt * 64 + rl + rg;
      if (pos < cnt) {
        unsigned short* hrow = H + (size_t)(base_e + pos) * HIDDEN;
#pragma unroll
        for (int j = 0; j < 4; ++j) {
          int col = n0 + wn * 64 + j * 16 + l15;
          float v = acc[i][j][rg] + b1e[col];
          float g = 0.5f * v * (1.0f + erff(v * 0.70710678118654752f));
          hrow[col] = (unsigned short)f2bf(g);
        }
      }
    }
  }
}

// ---------------- FFN layer 2: out += w_r * (H_e @ W2[e] + b2[e]) ----------------
// grid (16, 128, 2): x = n-tile (64 over EMBED), y = e*16 + mt, z = K-chunk of 2048
__global__ __launch_bounds__(256, 4) void ffn2_kernel(
    const unsigned short* __restrict__ H, const float* __restrict__ w2,
    const float* __restrict__ b2, const int* __restrict__ count,
    const int* __restrict__ base, const int* __restrict__ row_token,
    const float* __restrict__ row_w, float* __restrict__ out) {
  int nt = blockIdx.x;
  int e  = blockIdx.y >> 4;
  int mt = blockIdx.y & 15;
  int kc = blockIdx.z;
  int cnt = count[e];
  if (mt * 64 >= cnt) return;
  int base_e = base[e];
  int n0 = nt * 64;
  const int KC = HIDDEN / 2;  // 2048
  const float* w2e = w2 + (size_t)e * HIDDEN * EMBED + (size_t)kc * KC * EMBED;

  __shared__ __align__(16) short As[2][64 * LDA];
  __shared__ __align__(16) short Bs[2][64 * LDA];

  int tid = threadIdx.x;
  int arow = tid >> 2;
  int akq  = (tid & 3) * 8;
  int a_pos = mt * 64 + arow;
  bool a_ok = (a_pos < cnt);
  const unsigned short* a_src =
      H + (size_t)(base_e + (a_ok ? a_pos : 0)) * HIDDEN + kc * KC + akq;
  short* As_dst0 = &As[0][arow * LDA + akq];
  short* As_dst1 = &As[1][arow * LDA + akq];

  int bn  = tid & 63;
  int bk0 = (tid >> 6) * 8;
  const float* b_src = w2e + (size_t)(n0 + bn);
  short* Bs_dst0 = &Bs[0][bn * LDA + bk0];
  short* Bs_dst1 = &Bs[1][bn * LDA + bk0];

  int lane = tid & 63, wv = tid >> 6;
  int wm = wv & 1, wn = wv >> 1;
  int quad = lane >> 4, l15 = lane & 15;

  f32x4 acc[2][2];
#pragma unroll
  for (int i = 0; i < 2; ++i)
#pragma unroll
    for (int j = 0; j < 2; ++j) acc[i][j] = (f32x4){0.f, 0.f, 0.f, 0.f};

  // prefetch k=0
  short8 av = *(const short8*)(a_src);
  float bv[8];
#pragma unroll
  for (int j = 0; j < 8; ++j) bv[j] = b_src[(size_t)(bk0 + j) * EMBED];

  int cur = 0;
  for (int kk = 0; kk < KC; kk += 32) {
    short8 bpk;
#pragma unroll
    for (int j = 0; j < 8; ++j) bpk[j] = f2bf(bv[j]);
    short* ad = cur ? As_dst1 : As_dst0;
    short* bd = cur ? Bs_dst1 : Bs_dst0;
    *(short8*)ad = av;
    *(short8*)bd = bpk;
    __syncthreads();

    int kn = kk + 32; if (kn >= KC) kn = 0;
    av = *(const short8*)(a_src + kn);
#pragma unroll
    for (int j = 0; j < 8; ++j) bv[j] = b_src[(size_t)(kn + bk0 + j) * EMBED];

    const short* Ab = &As[cur][(wm * 32 + l15) * LDA + quad * 8];
    const short* Bb = &Bs[cur][(wn * 32 + l15) * LDA + quad * 8];
    short8 af[2], bf2[2];
#pragma unroll
    for (int i = 0; i < 2; ++i) af[i] = *(const short8*)(Ab + i * 16 * LDA);
#pragma unroll
    for (int j = 0; j < 2; ++j) bf2[j] = *(const short8*)(Bb + j * 16 * LDA);
#pragma unroll
    for (int i = 0; i < 2; ++i)
#pragma unroll
      for (int j = 0; j < 2; ++j)
        acc[i][j] = __builtin_amdgcn_mfma_f32_16x16x32_bf16(af[i], bf2[j], acc[i][j], 0, 0, 0);
    cur ^= 1;
  }

  const float* b2e = b2 + e * EMBED;
#pragma unroll
  for (int i = 0; i < 2; ++i) {
    int rl = wm * 32 + i * 16 + quad * 4;
#pragma unroll
    for (int rg = 0; rg < 4; ++rg) {
      int pos = mt * 64 + rl + rg;
      if (pos < cnt) {
        int r = base_e + pos;
        int tok = row_token[r];
        float wgt = row_w[r];
        float* orow = out + (size_t)tok * EMBED;
#pragma unroll
        for (int j = 0; j < 2; ++j) {
          int col = n0 + wn * 32 + j * 16 + l15;
          float v = acc[i][j][rg] + (kc == 0 ? b2e[col] : 0.f);
          atomicAdd(orow + col, v * wgt);
        }
      }
    }
  }
}

extern "C" void kernel_launch(void* const* d_in, const int* in_sizes, int n_in,
                              void* d_out, int out_size, void* d_ws, size_t ws_size,
                              hipStream_t stream) {
  (void)n_in; (void)ws_size;
  const float* x   = (const float*)d_in[0];
  const float* gw  = (const float*)d_in[1];
  const float* w1  = (const float*)d_in[2];
  const float* b1  = (const float*)d_in[3];
  const float* w2  = (const float*)d_in[4];
  const float* b2  = (const float*)d_in[5];
  float* out = (float*)d_out;
  int T = in_sizes[0] / EMBED;  // 1024

  char* w = (char*)d_ws;
  int*    count     = (int*)(w + 0);        // 8 ints
  int*    base      = (int*)(w + 32);       // 8 ints
  int2*   t_idx     = (int2*)(w + 1024);    // T int2
  float2* t_w       = (float2*)(w + 1024 + 8192);
  int*    row_token = (int*)(w + 32768);    // ROWS_CAP ints
  float*  row_w     = (float*)(w + 49152);  // ROWS_CAP floats
  unsigned short* H = (unsigned short*)(w + 65536);  // ROWS_CAP x HIDDEN bf16

  hipMemsetAsync(count, 0, 32, stream);
  hipMemsetAsync(out, 0, (size_t)out_size * sizeof(float), stream);
  router_kernel<<<T / 4, 256, 0, stream>>>(x, gw, count, t_idx, t_w);
  assign_kernel<<<1, 256, 0, stream>>>(count, base, t_idx, t_w, row_token, row_w, T);
  ffn1_kernel<<<dim3(HIDDEN / 128, 128), 256, 0, stream>>>(x, w1, b1, count, base, row_token, H);
  ffn2_kernel<<<dim3(EMBED / 64, 128, 2), 256, 0, stream>>>(H, w2, b2, count, base, row_token, row_w, out);
}

// Round 3
// 498.328 us; speedup vs baseline: 1.4970x; 1.4970x over previous
//
#include <hip/hip_runtime.h>
#include <math.h>

#define EMBED 1024
#define HIDDEN 4096
#define ROWS_CAP 3072

// workspace layout (bytes)
#define WS_COUNT   0
#define WS_BASE    64
#define WS_TIDX    4096
#define WS_TW      12288
#define WS_ROWTOK  20480
#define WS_ROWW    32768
#define WS_XB      65536
#define WS_H       2162688ULL
#define WS_W1R     27328512ULL
#define WS_W2R     94437376ULL
#define WS_NEED    161546240ULL

typedef short short8 __attribute__((ext_vector_type(8)));
typedef float f32x4 __attribute__((ext_vector_type(4)));

typedef const __attribute__((address_space(1))) unsigned int* gas_t;
typedef __attribute__((address_space(3))) unsigned int* las_t;

__device__ __forceinline__ void gl16(const void* g, void* l) {
  __builtin_amdgcn_global_load_lds((gas_t)g, (las_t)l, 16, 0, 0);
}

__device__ __forceinline__ short f2bf(float f) {
  __bf16 h = (__bf16)f;
  return __builtin_bit_cast(short, h);
}

__device__ __forceinline__ short8 pack8(float4 a, float4 b) {
  short8 r;
  r[0] = f2bf(a.x); r[1] = f2bf(a.y); r[2] = f2bf(a.z); r[3] = f2bf(a.w);
  r[4] = f2bf(b.x); r[5] = f2bf(b.y); r[6] = f2bf(b.z); r[7] = f2bf(b.w);
  return r;
}

// ---------------- router ----------------
__global__ __launch_bounds__(256) void router_kernel(
    const float* __restrict__ x, const float* __restrict__ gw,
    int* __restrict__ count, int2* __restrict__ t_idx, float2* __restrict__ t_w) {
  int t = blockIdx.x * 4 + (threadIdx.x >> 6);
  int lane = threadIdx.x & 63;
  const float* xr = x + (size_t)t * EMBED;
  float acc[8] = {0.f,0.f,0.f,0.f,0.f,0.f,0.f,0.f};
#pragma unroll
  for (int c = 0; c < 4; ++c) {
    float4 xv = *(const float4*)(xr + lane * 4 + c * 256);
#pragma unroll
    for (int e = 0; e < 8; ++e) {
      float4 gv = *(const float4*)(gw + e * EMBED + lane * 4 + c * 256);
      acc[e] += xv.x * gv.x + xv.y * gv.y + xv.z * gv.z + xv.w * gv.w;
    }
  }
#pragma unroll
  for (int e = 0; e < 8; ++e) {
#pragma unroll
    for (int off = 32; off > 0; off >>= 1) acc[e] += __shfl_down(acc[e], off);
  }
  if (lane == 0) {
    float m = acc[0];
#pragma unroll
    for (int e = 1; e < 8; ++e) m = fmaxf(m, acc[e]);
    float p[8]; float s = 0.f;
#pragma unroll
    for (int e = 0; e < 8; ++e) { p[e] = expf(acc[e] - m); s += p[e]; }
    float inv = 1.0f / s;
#pragma unroll
    for (int e = 0; e < 8; ++e) p[e] *= inv;
    int i0 = 0; float p0 = p[0];
#pragma unroll
    for (int e = 1; e < 8; ++e) if (p[e] > p0) { p0 = p[e]; i0 = e; }
    int i1 = -1; float p1 = -1.f;
#pragma unroll
    for (int e = 0; e < 8; ++e) if (e != i0 && p[e] > p1) { p1 = p[e]; i1 = e; }
    float denom = p0 + p1 + 1e-9f;
    atomicAdd(&count[i0], 1);
    atomicAdd(&count[i1], 1);
    t_idx[t] = make_int2(i0, i1);
    t_w[t] = make_float2(p0 / denom, p1 / denom);
  }
}

// ---------------- assign ----------------
__global__ __launch_bounds__(256) void assign_kernel(
    const int* __restrict__ count, int* __restrict__ base,
    const int2* __restrict__ t_idx, const float2* __restrict__ t_w,
    int* __restrict__ row_token, float* __restrict__ row_w, int T) {
  __shared__ int s_base[8];
  __shared__ int s_cur[8];
  int tid = threadIdx.x;
  for (int i = tid; i < ROWS_CAP; i += 256) row_token[i] = -1;
  if (tid == 0) {
    int b = 0;
    for (int e = 0; e < 8; ++e) {
      s_base[e] = b; base[e] = b;
      b += (count[e] + 127) & ~127;
    }
  }
  if (tid < 8) s_cur[tid] = 0;
  __syncthreads();
  for (int t = tid; t < T; t += 256) {
    int2 ii = t_idx[t]; float2 ww = t_w[t];
    int p = atomicAdd(&s_cur[ii.x], 1);
    int r = s_base[ii.x] + p;
    row_token[r] = t; row_w[r] = ww.x;
    p = atomicAdd(&s_cur[ii.y], 1);
    r = s_base[ii.y] + p;
    row_token[r] = t; row_w[r] = ww.y;
  }
}

// ---------------- x fp32 -> bf16 ----------------
__global__ __launch_bounds__(256) void convert_x_kernel(
    const float* __restrict__ x, unsigned short* __restrict__ xb) {
  int i = (blockIdx.x * 256 + threadIdx.x) * 4;
  float4 v = *(const float4*)(x + i);
  ushort4 o;
  o.x = (unsigned short)f2bf(v.x); o.y = (unsigned short)f2bf(v.y);
  o.z = (unsigned short)f2bf(v.z); o.w = (unsigned short)f2bf(v.w);
  *(ushort4*)(xb + i) = o;
}

// ---------------- repack weights fp32 [k][n] -> bf16 tiles [e][nt][kc][n128][k32] ----------------
// grid 16384: b<8192 -> w1 (e*32nt*32kc), else w2 (e*8nt*128kc)
__global__ __launch_bounds__(256) void repack_w_kernel(
    const float* __restrict__ w1, const float* __restrict__ w2,
    unsigned short* __restrict__ w1r, unsigned short* __restrict__ w2r) {
  __shared__ float tile[32 * 129];
  int b = blockIdx.x;
  const float* src; unsigned short* dst; int N;
  if (b < 8192) {
    int kc = b & 31, nt = (b >> 5) & 31, e = b >> 10;
    N = HIDDEN;
    src = w1 + (size_t)e * EMBED * HIDDEN + (size_t)(kc * 32) * HIDDEN + nt * 128;
    dst = w1r + (size_t)b * 4096;
  } else {
    int b2 = b - 8192;
    int kc = b2 & 127, nt = (b2 >> 7) & 7, e = b2 >> 10;
    N = EMBED;
    src = w2 + (size_t)e * HIDDEN * EMBED + (size_t)(kc * 32) * EMBED + nt * 128;
    dst = w2r + (size_t)b2 * 4096;
  }
  int t = threadIdx.x;
#pragma unroll
  for (int r = 0; r < 4; ++r) {
    int idx = r * 256 + t;
    int k = idx >> 5;
    int n4 = (idx & 31) * 4;
    float4 v = *(const float4*)(src + (size_t)k * N + n4);
    tile[k * 129 + n4 + 0] = v.x;
    tile[k * 129 + n4 + 1] = v.y;
    tile[k * 129 + n4 + 2] = v.z;
    tile[k * 129 + n4 + 3] = v.w;
  }
  __syncthreads();
  int n = t >> 1, half = t & 1;
  short8 o0, o1;
#pragma unroll
  for (int j = 0; j < 8; ++j) o0[j] = f2bf(tile[(half * 16 + j) * 129 + n]);
#pragma unroll
  for (int j = 0; j < 8; ++j) o1[j] = f2bf(tile[(half * 16 + 8 + j) * 129 + n]);
  *(short8*)(dst + n * 32 + half * 16) = o0;
  *(short8*)(dst + n * 32 + half * 16 + 8) = o1;
}

// ---------------- FFN1 (m97 structure): H = gelu(Xb @ W1r + b1) ----------------
// grid (32, 64): x = n-tile (128 over HIDDEN), y = e*8 + mt (128-row tiles)
__global__ __launch_bounds__(256) void ffn1_kernel(
    const unsigned short* __restrict__ xb, const unsigned short* __restrict__ w1r,
    const float* __restrict__ b1, const int* __restrict__ count,
    const int* __restrict__ base, const int* __restrict__ row_token,
    unsigned short* __restrict__ H) {
  int nt = blockIdx.x;
  int e  = blockIdx.y >> 3;
  int mt = blockIdx.y & 7;
  int cnt = count[e];
  if (mt * 128 >= cnt) return;
  int base_e = base[e];
  int n0 = nt * 128;

  __shared__ __align__(16) short As[128 * 32];
  __shared__ __align__(16) short Bs[128 * 32];

  int tid = threadIdx.x, wv = tid >> 6, lane = tid & 63;
  const unsigned short* aptr[2];
#pragma unroll
  for (int c = 0; c < 2; ++c) {
    int flat = c * 256 + tid;
    int row = flat >> 2;
    int pos = mt * 128 + row;
    int tok = (pos < cnt) ? row_token[base_e + pos] : 0;
    if (tok < 0) tok = 0;
    aptr[c] = xb + (size_t)tok * EMBED + (flat & 3) * 8;
  }
  const unsigned short* btile = w1r + ((size_t)(e * 32 + nt) * 32) * 4096 + tid * 8;

  short* As_st = As + wv * 512;   // wave base; lane auto-offset = lane*16B
  short* Bs_st = Bs + wv * 512;

  int wm = wv & 1, wn = wv >> 1;
  int quad = lane >> 4, l15 = lane & 15;
  const short* Afr = As + (wm * 64 + l15) * 32 + quad * 8;
  const short* Bfr = Bs + (wn * 64 + l15) * 32 + quad * 8;

  f32x4 acc[4][4];
#pragma unroll
  for (int i = 0; i < 4; ++i)
#pragma unroll
    for (int j = 0; j < 4; ++j) acc[i][j] = (f32x4){0.f, 0.f, 0.f, 0.f};

  for (int kc = 0; kc < 32; ++kc) {
    gl16(aptr[0] + kc * 32, As_st);
    gl16(aptr[1] + kc * 32, As_st + 2048);
    gl16(btile + (size_t)kc * 4096, Bs_st);
    gl16(btile + (size_t)kc * 4096 + 2048, Bs_st + 2048);
    __syncthreads();
    short8 a[4], bb[4];
#pragma unroll
    for (int i = 0; i < 4; ++i) a[i]  = *(const short8*)(Afr + i * 16 * 32);
#pragma unroll
    for (int j = 0; j < 4; ++j) bb[j] = *(const short8*)(Bfr + j * 16 * 32);
#pragma unroll
    for (int i = 0; i < 4; ++i)
#pragma unroll
      for (int j = 0; j < 4; ++j)
        acc[i][j] = __builtin_amdgcn_mfma_f32_16x16x32_bf16(a[i], bb[j], acc[i][j], 0, 0, 0);
    __syncthreads();
  }

  const float* b1e = b1 + e * HIDDEN;
#pragma unroll
  for (int i = 0; i < 4; ++i) {
    int rl = wm * 64 + i * 16 + quad * 4;
#pragma unroll
    for (int rg = 0; rg < 4; ++rg) {
      int pos = mt * 128 + rl + rg;
      if (pos < cnt) {
        unsigned short* hrow = H + (size_t)(base_e + pos) * HIDDEN;
#pragma unroll
        for (int j = 0; j < 4; ++j) {
          int col = n0 + wn * 64 + j * 16 + l15;
          float v = acc[i][j][rg] + b1e[col];
          float g = 0.5f * v * (1.0f + erff(v * 0.70710678118654752f));
          hrow[col] = (unsigned short)f2bf(g);
        }
      }
    }
  }
}

// ---------------- FFN2 (m97 structure): out += w_r * (H @ W2r + b2) ----------------
// grid (8, 64, 4): x = n-tile (128 over EMBED), y = e*8 + mt, z = K split (1024 each)
__global__ __launch_bounds__(256) void ffn2_kernel(
    const unsigned short* __restrict__ H, const unsigned short* __restrict__ w2r,
    const float* __restrict__ b2, const int* __restrict__ count,
    const int* __restrict__ base, const int* __restrict__ row_token,
    const float* __restrict__ row_w, float* __restrict__ out) {
  int nt = blockIdx.x;
  int e  = blockIdx.y >> 3;
  int mt = blockIdx.y & 7;
  int sp = blockIdx.z;
  int cnt = count[e];
  if (mt * 128 >= cnt) return;
  int base_e = base[e];
  int n0 = nt * 128;

  __shared__ __align__(16) short As[128 * 32];
  __shared__ __align__(16) short Bs[128 * 32];

  int tid = threadIdx.x, wv = tid >> 6, lane = tid & 63;
  const unsigned short* aptr[2];
#pragma unroll
  for (int c = 0; c < 2; ++c) {
    int flat = c * 256 + tid;
    int row = flat >> 2;
    aptr[c] = H + (size_t)(base_e + mt * 128 + row) * HIDDEN + sp * 1024 + (flat & 3) * 8;
  }
  const unsigned short* btile =
      w2r + ((size_t)(e * 8 + nt) * 128 + sp * 32) * 4096 + tid * 8;

  short* As_st = As + wv * 512;
  short* Bs_st = Bs + wv * 512;

  int wm = wv & 1, wn = wv >> 1;
  int quad = lane >> 4, l15 = lane & 15;
  const short* Afr = As + (wm * 64 + l15) * 32 + quad * 8;
  const short* Bfr = Bs + (wn * 64 + l15) * 32 + quad * 8;

  f32x4 acc[4][4];
#pragma unroll
  for (int i = 0; i < 4; ++i)
#pragma unroll
    for (int j = 0; j < 4; ++j) acc[i][j] = (f32x4){0.f, 0.f, 0.f, 0.f};

  for (int kc = 0; kc < 32; ++kc) {
    gl16(aptr[0] + kc * 32, As_st);
    gl16(aptr[1] + kc * 32, As_st + 2048);
    gl16(btile + (size_t)kc * 4096, Bs_st);
    gl16(btile + (size_t)kc * 4096 + 2048, Bs_st + 2048);
    __syncthreads();
    short8 a[4], bb[4];
#pragma unroll
    for (int i = 0; i < 4; ++i) a[i]  = *(const short8*)(Afr + i * 16 * 32);
#pragma unroll
    for (int j = 0; j < 4; ++j) bb[j] = *(const short8*)(Bfr + j * 16 * 32);
#pragma unroll
    for (int i = 0; i < 4; ++i)
#pragma unroll
      for (int j = 0; j < 4; ++j)
        acc[i][j] = __builtin_amdgcn_mfma_f32_16x16x32_bf16(a[i], bb[j], acc[i][j], 0, 0, 0);
    __syncthreads();
  }

  const float* b2e = b2 + e * EMBED;
#pragma unroll
  for (int i = 0; i < 4; ++i) {
    int rl = wm * 64 + i * 16 + quad * 4;
#pragma unroll
    for (int rg = 0; rg < 4; ++rg) {
      int pos = mt * 128 + rl + rg;
      if (pos < cnt) {
        int r = base_e + pos;
        int tok = row_token[r];
        float wgt = row_w[r];
        float* orow = out + (size_t)tok * EMBED;
#pragma unroll
        for (int j = 0; j < 4; ++j) {
          int col = n0 + wn * 64 + j * 16 + l15;
          float v = acc[i][j][rg] + (sp == 0 ? b2e[col] : 0.f);
          atomicAdd(orow + col, v * wgt);
        }
      }
    }
  }
}

// ================= fallback (R1-proven) used when ws_size too small =================
__global__ __launch_bounds__(256) void ffn1_fb_kernel(
    const float* __restrict__ x, const float* __restrict__ w1,
    const float* __restrict__ b1, const int* __restrict__ count,
    const int* __restrict__ base, const int* __restrict__ row_token,
    unsigned short* __restrict__ H) {
  int nt = blockIdx.x;
  int e  = blockIdx.y >> 3;
  int mt = blockIdx.y & 7;
  int cnt = count[e];
  if (mt * 128 >= cnt) return;
  int base_e = base[e];
  int n0 = nt * 128;
  const float* w1e = w1 + (size_t)e * EMBED * HIDDEN;

  __shared__ __align__(16) short As[128 * 40];
  __shared__ __align__(16) short Bs[128 * 40];

  int tid = threadIdx.x;
  int arow = tid >> 1;
  int akq  = (tid & 1) * 16;
  int a_pos = mt * 128 + arow;
  int a_tok = (a_pos < cnt) ? row_token[base_e + a_pos] : -1;
  const float* a_src = x + (size_t)(a_tok < 0 ? 0 : a_tok) * EMBED + akq;
  short* As_dst = &As[arow * 40 + akq];
  int bn  = tid & 127;
  int bk0 = (tid >> 7) * 16;
  const float* b_src = w1e + (size_t)(n0 + bn);
  short* Bs_dst = &Bs[bn * 40 + bk0];

  int lane = tid & 63, wv = tid >> 6;
  int quad = lane >> 4, l15 = lane & 15;
  const short* Abase = &As[((wv & 1) * 64 + l15) * 40 + quad * 8];
  const short* Bbase = &Bs[((wv >> 1) * 64 + l15) * 40 + quad * 8];

  f32x4 acc[4][4];
#pragma unroll
  for (int i = 0; i < 4; ++i)
#pragma unroll
    for (int j = 0; j < 4; ++j) acc[i][j] = (f32x4){0.f, 0.f, 0.f, 0.f};

  for (int kk = 0; kk < EMBED; kk += 32) {
    short8 av0 = {0,0,0,0,0,0,0,0}, av1 = {0,0,0,0,0,0,0,0};
    if (a_tok >= 0) {
      const float4* p = (const float4*)(a_src + kk);
      av0 = pack8(p[0], p[1]); av1 = pack8(p[2], p[3]);
    }
    float bv[16];
#pragma unroll
    for (int j = 0; j < 16; ++j) bv[j] = b_src[(size_t)(kk + bk0 + j) * HIDDEN];
    short8 blo, bhi;
#pragma unroll
    for (int j = 0; j < 8; ++j) { blo[j] = f2bf(bv[j]); bhi[j] = f2bf(bv[j + 8]); }
    *(short8*)As_dst = av0; *(short8*)(As_dst + 8) = av1;
    *(short8*)Bs_dst = blo; *(short8*)(Bs_dst + 8) = bhi;
    __syncthreads();
    short8 af[4], bfv[4];
#pragma unroll
    for (int i = 0; i < 4; ++i) {
      af[i]  = *(const short8*)(Abase + i * 16 * 40);
      bfv[i] = *(const short8*)(Bbase + i * 16 * 40);
    }
#pragma unroll
    for (int i = 0; i < 4; ++i)
#pragma unroll
      for (int j = 0; j < 4; ++j)
        acc[i][j] = __builtin_amdgcn_mfma_f32_16x16x32_bf16(af[i], bfv[j], acc[i][j], 0, 0, 0);
    __syncthreads();
  }

  const float* b1e = b1 + e * HIDDEN;
#pragma unroll
  for (int i = 0; i < 4; ++i) {
    int rl = (wv & 1) * 64 + i * 16 + quad * 4;
#pragma unroll
    for (int rg = 0; rg < 4; ++rg) {
      int pos = mt * 128 + rl + rg;
      if (pos < cnt) {
        unsigned short* hrow = H + (size_t)(base_e + pos) * HIDDEN;
#pragma unroll
        for (int j = 0; j < 4; ++j) {
          int col = n0 + (wv >> 1) * 64 + j * 16 + l15;
          float v = acc[i][j][rg] + b1e[col];
          float g = 0.5f * v * (1.0f + erff(v * 0.70710678118654752f));
          hrow[col] = (unsigned short)f2bf(g);
        }
      }
    }
  }
}

__global__ __launch_bounds__(256) void ffn2_fb_kernel(
    const unsigned short* __restrict__ H, const float* __restrict__ w2,
    const float* __restrict__ b2, const int* __restrict__ count,
    const int* __restrict__ base, const int* __restrict__ row_token,
    const float* __restrict__ row_w, float* __restrict__ out) {
  int nt = blockIdx.x;
  int e  = blockIdx.y >> 3;
  int mt = blockIdx.y & 7;
  int cnt = count[e];
  if (mt * 128 >= cnt) return;
  int base_e = base[e];
  int n0 = nt * 64;
  const float* w2e = w2 + (size_t)e * HIDDEN * EMBED;

  __shared__ __align__(16) short As[128 * 40];
  __shared__ __align__(16) short Bs[64 * 40];

  int tid = threadIdx.x;
  int arow = tid >> 1;
  int akq  = (tid & 1) * 16;
  int a_pos = mt * 128 + arow;
  bool a_ok = (a_pos < cnt);
  const unsigned short* a_src = H + (size_t)(base_e + (a_ok ? a_pos : 0)) * HIDDEN + akq;
  short* As_dst = &As[arow * 40 + akq];
  int bn  = tid & 63;
  int bk0 = (tid >> 6) * 8;
  const float* b_src = w2e + (size_t)(n0 + bn);
  short* Bs_dst = &Bs[bn * 40 + bk0];

  int lane = tid & 63, wv = tid >> 6;
  int quad = lane >> 4, l15 = lane & 15;
  const short* Abase = &As[((wv & 1) * 64 + l15) * 40 + quad * 8];
  const short* Bbase = &Bs[((wv >> 1) * 32 + l15) * 40 + quad * 8];

  f32x4 acc[4][2];
#pragma unroll
  for (int i = 0; i < 4; ++i)
#pragma unroll
    for (int j = 0; j < 2; ++j) acc[i][j] = (f32x4){0.f, 0.f, 0.f, 0.f};

  for (int kk = 0; kk < HIDDEN; kk += 32) {
    short8 av0 = {0,0,0,0,0,0,0,0}, av1 = {0,0,0,0,0,0,0,0};
    if (a_ok) {
      const short8* p = (const short8*)(a_src + kk);
      av0 = p[0]; av1 = p[1];
    }
    float bv[8];
#pragma unroll
    for (int j = 0; j < 8; ++j) bv[j] = b_src[(size_t)(kk + bk0 + j) * EMBED];
    short8 bpk;
#pragma unroll
    for (int j = 0; j < 8; ++j) bpk[j] = f2bf(bv[j]);
    *(short8*)As_dst = av0; *(short8*)(As_dst + 8) = av1;
    *(short8*)Bs_dst = bpk;
    __syncthreads();
    short8 af[4], bf2[2];
#pragma unroll
    for (int i = 0; i < 4; ++i) af[i] = *(const short8*)(Abase + i * 16 * 40);
#pragma unroll
    for (int j = 0; j < 2; ++j) bf2[j] = *(const short8*)(Bbase + j * 16 * 40);
#pragma unroll
    for (int i = 0; i < 4; ++i)
#pragma unroll
      for (int j = 0; j < 2; ++j)
        acc[i][j] = __builtin_amdgcn_mfma_f32_16x16x32_bf16(af[i], bf2[j], acc[i][j], 0, 0, 0);
    __syncthreads();
  }

  const float* b2e = b2 + e * EMBED;
#pragma unroll
  for (int i = 0; i < 4; ++i) {
    int rl = (wv & 1) * 64 + i * 16 + quad * 4;
#pragma unroll
    for (int rg = 0; rg < 4; ++rg) {
      int pos = mt * 128 + rl + rg;
      if (pos < cnt) {
        int r = base_e + pos;
        int tok = row_token[r];
        float wgt = row_w[r];
        float* orow = out + (size_t)tok * EMBED;
#pragma unroll
        for (int j = 0; j < 2; ++j) {
          int col = n0 + (wv >> 1) * 32 + j * 16 + l15;
          float v = acc[i][j][rg] + b2e[col];
          atomicAdd(orow + col, v * wgt);
        }
      }
    }
  }
}

extern "C" void kernel_launch(void* const* d_in, const int* in_sizes, int n_in,
                              void* d_out, int out_size, void* d_ws, size_t ws_size,
                              hipStream_t stream) {
  (void)n_in;
  const float* x   = (const float*)d_in[0];
  const float* gw  = (const float*)d_in[1];
  const float* w1  = (const float*)d_in[2];
  const float* b1  = (const float*)d_in[3];
  const float* w2  = (const float*)d_in[4];
  const float* b2  = (const float*)d_in[5];
  float* out = (float*)d_out;
  int T = in_sizes[0] / EMBED;  // 1024

  char* w = (char*)d_ws;
  int*    count     = (int*)(w + WS_COUNT);
  int*    base      = (int*)(w + WS_BASE);
  int2*   t_idx     = (int2*)(w + WS_TIDX);
  float2* t_w       = (float2*)(w + WS_TW);
  int*    row_token = (int*)(w + WS_ROWTOK);
  float*  row_w     = (float*)(w + WS_ROWW);
  unsigned short* xb  = (unsigned short*)(w + WS_XB);
  unsigned short* H   = (unsigned short*)(w + WS_H);
  unsigned short* w1r = (unsigned short*)(w + WS_W1R);
  unsigned short* w2r = (unsigned short*)(w + WS_W2R);

  hipMemsetAsync(count, 0, 32, stream);
  hipMemsetAsync(out, 0, (size_t)out_size * sizeof(float), stream);
  router_kernel<<<T / 4, 256, 0, stream>>>(x, gw, count, t_idx, t_w);
  assign_kernel<<<1, 256, 0, stream>>>(count, base, t_idx, t_w, row_token, row_w, T);

  if (ws_size >= WS_NEED) {
    convert_x_kernel<<<(T * EMBED) / 1024, 256, 0, stream>>>(x, xb);
    repack_w_kernel<<<16384, 256, 0, stream>>>(w1, w2, w1r, w2r);
    ffn1_kernel<<<dim3(HIDDEN / 128, 64), 256, 0, stream>>>(xb, w1r, b1, count, base, row_token, H);
    ffn2_kernel<<<dim3(EMBED / 128, 64, 4), 256, 0, stream>>>(H, w2r, b2, count, base, row_token, row_w, out);
  } else {
    ffn1_fb_kernel<<<dim3(HIDDEN / 128, 64), 256, 0, stream>>>(x, w1, b1, count, base, row_token, H);
    ffn2_fb_kernel<<<dim3(EMBED / 64, 64), 256, 0, stream>>>(H, w2, b2, count, base, row_token, row_w, out);
  }
}